// Round 2
// baseline (284.628 us; speedup 1.0000x reference)
//
#include <hip/hip_runtime.h>
#include <hip/hip_bf16.h>

#define S_DIM 128
#define N_PTS 384
#define CM    64
#define C_DIM 32
#define CZ    128
#define NC    (N_PTS*C_DIM)   // 12288

typedef __attribute__((ext_vector_type(8)))  __bf16 bf16x8;
typedef __attribute__((ext_vector_type(16))) float  f32x16;
typedef unsigned short u16;

__device__ __forceinline__ bf16x8 lds_frag(const u16* base, int byteoff){
  union { uint4 u; bf16x8 v; } x;
  x.u = *(const uint4*)((const char*)base + byteoff);
  return x.v;
}

// ---------------- kernel 0: transpose W [1024,128] (f32) -> Wt [128,1024] (bf16) ----------------
__global__ __launch_bounds__(256) void k_wt(const float* __restrict__ w_out,
                                            __hip_bfloat16* __restrict__ wt){
  int o = blockIdx.x*256 + threadIdx.x;     // 131072 total
  int z = o >> 10, k = o & 1023;
  wt[o] = (__hip_bfloat16)w_out[k*CZ + z];
}

// ---------------- kernel 1: LN + projections, transposed bf16 outputs ----------------
// A_ws[(n*32+c)*128 + s] = (LN(msa[s,n,:]) @ w_a)[c] * mask[s,n]   (bf16), same for B_ws/w_b
__global__ __launch_bounds__(256) void k_lnproj(
    const float* __restrict__ msa, const float* __restrict__ mask,
    const float* __restrict__ gamma, const float* __restrict__ beta,
    const float* __restrict__ wa, const float* __restrict__ wb,
    __hip_bfloat16* __restrict__ A_ws, __hip_bfloat16* __restrict__ B_ws){
  __shared__ float xl[4][CM];
  const int tid = threadIdx.x, wv = tid >> 6, l = tid & 63;
  const int wg = blockIdx.x*4 + wv;         // 0..49151
  const int s = wg / N_PTS, n = wg % N_PTS;

  float x = msa[(s*N_PTS + n)*CM + l];
  float sum = x;
  #pragma unroll
  for (int m = 1; m < 64; m <<= 1) sum += __shfl_xor(sum, m, 64);
  float mu = sum * (1.0f/64.0f);
  float dx = x - mu;
  float vs = dx*dx;
  #pragma unroll
  for (int m = 1; m < 64; m <<= 1) vs += __shfl_xor(vs, m, 64);
  float rstd = rsqrtf(vs*(1.0f/64.0f) + 1e-5f);
  float xn = dx*rstd*gamma[l] + beta[l];
  xl[wv][l] = xn;
  __syncthreads();

  float mk = mask[s*N_PTS + n];
  const float* W = (l < 32) ? wa : wb;
  __hip_bfloat16* O = (l < 32) ? A_ws : B_ws;
  const int c = l & 31;
  float acc = 0.f;
  #pragma unroll
  for (int m = 0; m < CM; ++m) acc += xl[wv][m] * W[m*C_DIM + c];
  O[(n*C_DIM + c)*S_DIM + s] = (__hip_bfloat16)(acc * mk);
}

// ---------------- kernel 2: fused (A^T B per 8x8 (i,j) tile) -> contract with W -> z ----------------
// grid (48,48), 512 threads (8 waves)
__global__ __launch_bounds__(512, 2) void k_fused(
    const __hip_bfloat16* __restrict__ A_ws, const __hip_bfloat16* __restrict__ B_ws,
    const __hip_bfloat16* __restrict__ Wt,  const float* __restrict__ b_out,
    const float* __restrict__ mask, float* __restrict__ out){
  __shared__ union {
    struct { u16 A[256*128]; u16 B[256*128]; } s1;   // 64KB + 64KB slabs [row m/n 256B each]
    struct { u16 P[64*1024]; u16 Wc[128*64]; } s2;   // 128KB pair matrix + 16KB W chunk
  } sh;
  __shared__ float nrm[64];

  const int tid = threadIdx.x;
  const int w = tid >> 6, l = tid & 63;
  const int bi = blockIdx.x, bj = blockIdx.y;

  // ---- per-pair mask norm ----
  if (tid < 64){
    int i = bi*8 + (tid >> 3), j = bj*8 + (tid & 7);
    float a = 0.f;
    for (int s = 0; s < S_DIM; ++s)
      a += mask[s*N_PTS + i] * mask[s*N_PTS + j];
    nrm[tid] = a;
  }

  // ---- prefetch first W chunk (regs) ----
  const char* WtB = (const char*)Wt;
  int wrow[2], wkb[2];
  uint4 pre[2];
  #pragma unroll
  for (int it = 0; it < 2; ++it){
    int o = (it*512 + tid) * 16;      // byte in 16KB chunk
    wrow[it] = o >> 7;                // z' row (128B rows)
    wkb[it]  = o & 127;
    pre[it] = *(const uint4*)(WtB + wrow[it]*2048 + 0*128 + wkb[it]);
  }

  // ---- stage A/B slabs into LDS (swizzled write) ----
  const char* Asrc = (const char*)(A_ws + (size_t)bi*256*S_DIM);   // 64KB contiguous
  const char* Bsrc = (const char*)(B_ws + (size_t)bj*256*S_DIM);
  u16* shA = sh.s1.A;
  u16* shB = sh.s1.B;
  #pragma unroll
  for (int it = 0; it < 8; ++it){
    int o = (it*512 + tid) * 16;
    int row = o >> 8, kb = o & 255;
    int dst = row*256 + (kb ^ ((row & 15) << 4));
    *(uint4*)((char*)shA + dst) = *(const uint4*)(Asrc + o);
    *(uint4*)((char*)shB + dst) = *(const uint4*)(Bsrc + o);
  }
  __syncthreads();

  // ---- stage B: 256x256 tile, K=128, 8 waves (2x4), each 128x64 = 4x2 blocks of 32x32 ----
  const int wr = w >> 2, wc = w & 3;
  f32x16 acc[4][2];
  #pragma unroll
  for (int mb = 0; mb < 4; ++mb)
    #pragma unroll
    for (int nb = 0; nb < 2; ++nb)
      #pragma unroll
      for (int r = 0; r < 16; ++r) acc[mb][nb][r] = 0.f;

  #pragma unroll
  for (int ks = 0; ks < 8; ++ks){
    const int k0b = (ks*16 + ((l >> 5) << 3)) * 2;   // byte offset of this lane's k run
    bf16x8 aF[4], bF[2];
    #pragma unroll
    for (int mb = 0; mb < 4; ++mb){
      int m = wr*128 + mb*32 + (l & 31);
      aF[mb] = lds_frag(shA, m*256 + (k0b ^ ((m & 15) << 4)));
    }
    #pragma unroll
    for (int nb = 0; nb < 2; ++nb){
      int n = wc*64 + nb*32 + (l & 31);
      bF[nb] = lds_frag(shB, n*256 + (k0b ^ ((n & 15) << 4)));
    }
    #pragma unroll
    for (int mb = 0; mb < 4; ++mb)
      #pragma unroll
      for (int nb = 0; nb < 2; ++nb)
        acc[mb][nb] = __builtin_amdgcn_mfma_f32_32x32x16_bf16(aF[mb], bF[nb], acc[mb][nb], 0, 0, 0);
  }
  __syncthreads();   // all slab reads done before P overwrites

  // ---- write P: pair p = (i_local)*8 + j_local, 1024 bf16 per pair (k = c*32+d), swizzled ----
  char* shP = (char*)sh.s2.P;
  const int d = l & 31;
  #pragma unroll
  for (int mb = 0; mb < 4; ++mb)
    #pragma unroll
    for (int nb = 0; nb < 2; ++nb){
      int p = (wr*4 + mb)*8 + (wc*2 + nb);
      #pragma unroll
      for (int r = 0; r < 16; ++r){
        int c = (r & 3) + ((r >> 2) << 3) + ((l >> 5) << 2);
        int kb = c*64 + d*2;
        *(__hip_bfloat16*)(shP + p*2048 + (kb ^ ((p & 15) << 4))) =
            (__hip_bfloat16)(acc[mb][nb][r]);
      }
    }
  __syncthreads();

  // ---- stage C: z[p, z'] = P[p,:] . Wt[z',:],  M=64, N=128, K=1024 ----
  const int cr = w >> 2, cc = w & 3;
  f32x16 zc;
  #pragma unroll
  for (int r = 0; r < 16; ++r) zc[r] = 0.f;
  u16* shWc = sh.s2.Wc;

  for (int ch = 0; ch < 16; ++ch){          // K chunks of 64
    #pragma unroll
    for (int it = 0; it < 2; ++it)
      *(uint4*)((char*)shWc + wrow[it]*128 + (wkb[it] ^ ((wrow[it] & 7) << 4))) = pre[it];
    if (ch < 15){
      #pragma unroll
      for (int it = 0; it < 2; ++it)
        pre[it] = *(const uint4*)(WtB + wrow[it]*2048 + (ch+1)*128 + wkb[it]);
    }
    __syncthreads();
    #pragma unroll
    for (int ks = 0; ks < 4; ++ks){
      int klocb = (ks*16 + ((l >> 5) << 3)) * 2;
      int p = cr*32 + (l & 31);
      int kgb = ch*128 + klocb;
      bf16x8 aF = lds_frag((const u16*)shP, p*2048 + (kgb ^ ((p & 15) << 4)));
      int z = cc*32 + (l & 31);
      bf16x8 bF = lds_frag(shWc, z*128 + (klocb ^ ((z & 7) << 4)));
      zc = __builtin_amdgcn_mfma_f32_32x32x16_bf16(aF, bF, zc, 0, 0, 0);
    }
    __syncthreads();
  }

  // ---- epilogue: + b_out, / (norm + 0.001), store fp32 ----
  const int z = cc*32 + (l & 31);
  const float bo = b_out[z];
  #pragma unroll
  for (int r = 0; r < 16; ++r){
    int p = cr*32 + (r & 3) + ((r >> 2) << 3) + ((l >> 5) << 2);
    int i = bi*8 + (p >> 3), j = bj*8 + (p & 7);
    float val = (zc[r] + bo) / (nrm[p] + 0.001f);
    out[((size_t)i*N_PTS + j)*CZ + z] = val;
  }
}

extern "C" void kernel_launch(void* const* d_in, const int* in_sizes, int n_in,
                              void* d_out, int out_size, void* d_ws, size_t ws_size,
                              hipStream_t stream) {
  (void)in_sizes; (void)n_in; (void)out_size; (void)ws_size;
  const float* msa   = (const float*)d_in[0];
  const float* mask  = (const float*)d_in[1];
  const float* gamma = (const float*)d_in[2];
  const float* beta  = (const float*)d_in[3];
  const float* wa    = (const float*)d_in[4];
  const float* wb    = (const float*)d_in[5];
  const float* wout  = (const float*)d_in[6];
  const float* bout  = (const float*)d_in[7];

  __hip_bfloat16* A_ws = (__hip_bfloat16*)d_ws;              // [12288][128] bf16
  __hip_bfloat16* B_ws = A_ws + (size_t)NC*S_DIM;            // [12288][128] bf16
  __hip_bfloat16* Wt   = B_ws + (size_t)NC*S_DIM;            // [128][1024] bf16
  float* outp = (float*)d_out;                               // [384][384][128] f32

  k_wt<<<512, 256, 0, stream>>>(wout, Wt);
  k_lnproj<<<12288, 256, 0, stream>>>(msa, mask, gamma, beta, wa, wb, A_ws, B_ws);
  dim3 g2(48, 48, 1);
  k_fused<<<g2, 512, 0, stream>>>(A_ws, B_ws, Wt, bout, mask, outp);
}

// Round 3
// 260.855 us; speedup vs baseline: 1.0911x; 1.0911x over previous
//
#include <hip/hip_runtime.h>
#include <hip/hip_bf16.h>

#define S_DIM 128
#define N_PTS 384
#define CM    64
#define C_DIM 32
#define CZ    128
#define NC    (N_PTS*C_DIM)   // 12288

typedef __attribute__((ext_vector_type(8)))  __bf16 bf16x8;
typedef __attribute__((ext_vector_type(16))) float  f32x16;
typedef unsigned short u16;
typedef unsigned int   u32;

__device__ __forceinline__ bf16x8 lds_frag(const void* base, int byteoff){
  union { uint4 u; bf16x8 v; } x;
  x.u = *(const uint4*)((const char*)base + byteoff);
  return x.v;
}
__device__ __forceinline__ u16 bf16bits(float f){
  union { float f; u32 u; } x; x.f = f;
  u32 r = (x.u + 0x7fff + ((x.u >> 16) & 1)) >> 16;   // RNE
  return (u16)r;
}

// ---------------- kernel 0: W [1024,128] (f32) -> Wt_perm [128 z][1024 mem-idx] (bf16) ------
// mem idx mi: e=mi&7, j=(mi>>3)&3, hi=(mi>>5)&1, Q=mi>>6 ; ks=Q*4+j ; pos=ks*16+hi*8+e
// pos -> original k: c = ((pos>>7)<<2)|(pos&3), d = (pos>>2)&31, k = c*32+d
__global__ __launch_bounds__(256) void k_wt(const float* __restrict__ w_out,
                                            __hip_bfloat16* __restrict__ wt){
  int o = blockIdx.x*256 + threadIdx.x;     // 131072 total
  int z = o >> 10, mi = o & 1023;
  int e = mi & 7, j = (mi >> 3) & 3, hi = (mi >> 5) & 1, Q = mi >> 6;
  int ks = Q*4 + j;
  int pos = ks*16 + hi*8 + e;
  int c = ((pos >> 7) << 2) | (pos & 3);
  int d = (pos >> 2) & 31;
  int k = c*32 + d;
  wt[o] = (__hip_bfloat16)w_out[k*CZ + z];
}

// ---------------- kernel 1: LN + projections, transposed bf16 outputs ----------------
__global__ __launch_bounds__(256) void k_lnproj(
    const float* __restrict__ msa, const float* __restrict__ mask,
    const float* __restrict__ gamma, const float* __restrict__ beta,
    const float* __restrict__ wa, const float* __restrict__ wb,
    __hip_bfloat16* __restrict__ A_ws, __hip_bfloat16* __restrict__ B_ws){
  __shared__ float xl[4][CM];
  const int tid = threadIdx.x, wv = tid >> 6, l = tid & 63;
  const int wg = blockIdx.x*4 + wv;
  const int s = wg / N_PTS, n = wg % N_PTS;

  float x = msa[(s*N_PTS + n)*CM + l];
  float sum = x;
  #pragma unroll
  for (int m = 1; m < 64; m <<= 1) sum += __shfl_xor(sum, m, 64);
  float mu = sum * (1.0f/64.0f);
  float dx = x - mu;
  float vs = dx*dx;
  #pragma unroll
  for (int m = 1; m < 64; m <<= 1) vs += __shfl_xor(vs, m, 64);
  float rstd = rsqrtf(vs*(1.0f/64.0f) + 1e-5f);
  float xn = dx*rstd*gamma[l] + beta[l];
  xl[wv][l] = xn;
  __syncthreads();

  float mk = mask[s*N_PTS + n];
  const float* W = (l < 32) ? wa : wb;
  __hip_bfloat16* O = (l < 32) ? A_ws : B_ws;
  const int c = l & 31;
  float acc = 0.f;
  #pragma unroll
  for (int m = 0; m < CM; ++m) acc += xl[wv][m] * W[m*C_DIM + c];
  O[(n*C_DIM + c)*S_DIM + s] = (__hip_bfloat16)(acc * mk);
}

// ---------------- kernel 2: fused ----------------
// grid (48,48), 512 threads (8 waves). Tile = 8x8 (i,j) pairs = 64 pairs.
__global__ __launch_bounds__(512, 1) void k_fused(
    const __hip_bfloat16* __restrict__ A_ws, const __hip_bfloat16* __restrict__ B_ws,
    const __hip_bfloat16* __restrict__ Wt,  const float* __restrict__ b_out,
    const float* __restrict__ mask, float* __restrict__ out){
  __shared__ union {
    struct { u16 A[256*128]; u16 B[256*128]; } s1;   // 64KB + 64KB slabs
    struct { u16 P[64*1024]; } s2;                   // 128KB P (pos-ordered, swizzled)
  } sh;
  __shared__ float nrm[64];

  const int tid = threadIdx.x;
  const int w = tid >> 6, l = tid & 63;
  const int hi = l >> 5, ln = l & 31;
  const int bi = blockIdx.x, bj = blockIdx.y;

  // ---- per-pair mask norm: 8 threads per pair ----
  {
    int p = tid >> 3, part = tid & 7;
    int i = bi*8 + (p >> 3), jj = bj*8 + (p & 7);
    float a = 0.f;
    #pragma unroll
    for (int s = part*16; s < part*16 + 16; ++s)
      a += mask[s*N_PTS + i] * mask[s*N_PTS + jj];
    a += __shfl_xor(a, 1, 64);
    a += __shfl_xor(a, 2, 64);
    a += __shfl_xor(a, 4, 64);
    if (part == 0) nrm[p] = a;
  }

  // ---- stage A/B slabs into LDS (swizzled dst, linear src) ----
  const char* Asrc = (const char*)(A_ws + (size_t)bi*256*S_DIM);   // 64KB contiguous
  const char* Bsrc = (const char*)(B_ws + (size_t)bj*256*S_DIM);
  u16* shA = sh.s1.A;
  u16* shB = sh.s1.B;
  #pragma unroll
  for (int it = 0; it < 8; ++it){
    int o = (it*512 + tid) * 16;
    int row = o >> 8, kb = o & 255;
    int dst = row*256 + (kb ^ ((row & 15) << 4));
    *(uint4*)((char*)shA + dst) = *(const uint4*)(Asrc + o);
    *(uint4*)((char*)shB + dst) = *(const uint4*)(Bsrc + o);
  }
  __syncthreads();

  // ---- stage B: 256x256 over K=128; 8 waves (2x4); wave = 128x64 = 4x2 blocks of 32 ----
  const int wr = w >> 2, wc = w & 3;
  f32x16 acc[4][2];
  #pragma unroll
  for (int mb = 0; mb < 4; ++mb)
    #pragma unroll
    for (int nb = 0; nb < 2; ++nb)
      #pragma unroll
      for (int r = 0; r < 16; ++r) acc[mb][nb][r] = 0.f;

  #pragma unroll
  for (int ks = 0; ks < 8; ++ks){
    const int k0b = ks*32 + hi*16;
    bf16x8 aF[4], bF[2];
    #pragma unroll
    for (int mb = 0; mb < 4; ++mb){
      int m = wr*128 + mb*32 + ln;
      aF[mb] = lds_frag(shA, m*256 + (k0b ^ ((m & 15) << 4)));
    }
    #pragma unroll
    for (int nb = 0; nb < 2; ++nb){
      int n = wc*64 + nb*32 + ln;
      bF[nb] = lds_frag(shB, n*256 + (k0b ^ ((n & 15) << 4)));
    }
    #pragma unroll
    for (int mb = 0; mb < 4; ++mb)
      #pragma unroll
      for (int nb = 0; nb < 2; ++nb)
        acc[mb][nb] = __builtin_amdgcn_mfma_f32_32x32x16_bf16(aF[mb], bF[nb], acc[mb][nb], 0, 0, 0);
  }
  __syncthreads();   // slab reads done before P overwrites

  // ---- write P (pos layout, b64-packed, full wave) ----
  // lane holds d=ln, hi half; reg r -> c=(r&3)+8*(r>>2)+4*hi; pos=(c>>2)*128+d*4+(c&3)
  // byte = p*2048 + (((c>>2)*256 + d*8 + (c&3)*2) ^ ((p&15)<<4))
  char* shP = (char*)sh.s2.P;
  #pragma unroll
  for (int mb = 0; mb < 4; ++mb)
    #pragma unroll
    for (int nb = 0; nb < 2; ++nb){
      int p = (wr*4 + mb)*8 + (wc*2 + nb);
      int base = p*2048, sw = (p & 15) << 4;
      #pragma unroll
      for (int g = 0; g < 4; ++g){
        u32 lo = (u32)bf16bits(acc[mb][nb][4*g + 0]) | ((u32)bf16bits(acc[mb][nb][4*g + 1]) << 16);
        u32 hi32 = (u32)bf16bits(acc[mb][nb][4*g + 2]) | ((u32)bf16bits(acc[mb][nb][4*g + 3]) << 16);
        uint2 v; v.x = lo; v.y = hi32;
        int off = ((2*g + hi)*256 + ln*8) ^ sw;
        *(uint2*)(shP + base + off) = v;
      }
    }
  __syncthreads();

  // ---- stage C: z[p][z'] = P[p,:] . Wt_perm[z',:], K=1024, barrier-free ----
  // wave (cr,cc): rows p in [cr*32,+32), cols z' in [cc*32,+32)
  const int cr = w >> 2, cc = w & 3;
  f32x16 zc;
  #pragma unroll
  for (int r = 0; r < 16; ++r) zc[r] = 0.f;

  const char* wbase = (const char*)Wt + (size_t)(cc*32 + ln)*2048 + hi*64;
  const char* prow  = shP + (cr*32 + ln)*2048;
  const int sw2 = (ln & 15) << 4;

  #pragma unroll 8
  for (int ks = 0; ks < 64; ++ks){
    bf16x8 aF = lds_frag(prow, (ks*32 + hi*16) ^ sw2);
    union { uint4 u; bf16x8 v; } bx;
    bx.u = *(const uint4*)(wbase + (ks >> 2)*128 + (ks & 3)*16);
    zc = __builtin_amdgcn_mfma_f32_32x32x16_bf16(aF, bx.v, zc, 0, 0, 0);
  }

  // ---- epilogue ----
  const int z = cc*32 + ln;
  const float bo = b_out[z];
  #pragma unroll
  for (int r = 0; r < 16; ++r){
    int p = cr*32 + (r & 3) + ((r >> 2) << 3) + (hi << 2);
    int i = bi*8 + (p >> 3), j = bj*8 + (p & 7);
    float val = (zc[r] + bo) / (nrm[p] + 0.001f);
    out[((size_t)i*N_PTS + j)*CZ + z] = val;
  }
}

extern "C" void kernel_launch(void* const* d_in, const int* in_sizes, int n_in,
                              void* d_out, int out_size, void* d_ws, size_t ws_size,
                              hipStream_t stream) {
  (void)in_sizes; (void)n_in; (void)out_size; (void)ws_size;
  const float* msa   = (const float*)d_in[0];
  const float* mask  = (const float*)d_in[1];
  const float* gamma = (const float*)d_in[2];
  const float* beta  = (const float*)d_in[3];
  const float* wa    = (const float*)d_in[4];
  const float* wb    = (const float*)d_in[5];
  const float* wout  = (const float*)d_in[6];
  const float* bout  = (const float*)d_in[7];

  __hip_bfloat16* A_ws = (__hip_bfloat16*)d_ws;              // [12288][128] bf16
  __hip_bfloat16* B_ws = A_ws + (size_t)NC*S_DIM;            // [12288][128] bf16
  __hip_bfloat16* Wt   = B_ws + (size_t)NC*S_DIM;            // [128][1024] bf16 (pos-permuted)
  float* outp = (float*)d_out;                               // [384][384][128] f32

  k_wt<<<512, 256, 0, stream>>>(wout, Wt);
  k_lnproj<<<12288, 256, 0, stream>>>(msa, mask, gamma, beta, wa, wb, A_ws, B_ws);
  dim3 g2(48, 48, 1);
  k_fused<<<g2, 512, 0, stream>>>(A_ws, B_ws, Wt, bout, mask, outp);
}

// Round 4
// 228.640 us; speedup vs baseline: 1.2449x; 1.1409x over previous
//
#include <hip/hip_runtime.h>
#include <hip/hip_bf16.h>

#define S_DIM 128
#define N_PTS 384
#define CM    64
#define C_DIM 32
#define CZ    128
#define NC    (N_PTS*C_DIM)   // 12288

typedef __attribute__((ext_vector_type(8)))  __bf16 bf16x8;
typedef __attribute__((ext_vector_type(16))) float  f32x16;
typedef unsigned short u16;
typedef unsigned int   u32;

__device__ __forceinline__ bf16x8 lds_frag(const void* base, int byteoff){
  union { uint4 u; bf16x8 v; } x;
  x.u = *(const uint4*)((const char*)base + byteoff);
  return x.v;
}
__device__ __forceinline__ u16 bf16bits(float f){
  union { float f; u32 u; } x; x.f = f;
  u32 r = (x.u + 0x7fff + ((x.u >> 16) & 1)) >> 16;   // RNE
  return (u16)r;
}

// ---------------- kernel 0: W [1024,128] (f32) -> Wt_perm [128 z][1024 mem-idx] (bf16) ------
// mem idx mi: e=mi&7, j=(mi>>3)&3, hi=(mi>>5)&1, Q=mi>>6 ; ks=Q*4+j ; pos=ks*16+hi*8+e
// pos -> original k: c = ((pos>>7)<<2)|(pos&3), d = (pos>>2)&31, k = c*32+d
__global__ __launch_bounds__(256) void k_wt(const float* __restrict__ w_out,
                                            __hip_bfloat16* __restrict__ wt){
  int o = blockIdx.x*256 + threadIdx.x;     // 131072 total
  int z = o >> 10, mi = o & 1023;
  int e = mi & 7, j = (mi >> 3) & 3, hi = (mi >> 5) & 1, Q = mi >> 6;
  int ks = Q*4 + j;
  int pos = ks*16 + hi*8 + e;
  int c = ((pos >> 7) << 2) | (pos & 3);
  int d = (pos >> 2) & 31;
  int k = c*32 + d;
  wt[o] = (__hip_bfloat16)w_out[k*CZ + z];
}

// ---------------- kernel 1: LN + projections via MFMA, coalesced transposed outputs --------
// grid = 384 (one block per n), 512 threads (8 waves).
__global__ __launch_bounds__(512) void k_lnproj(
    const float* __restrict__ msa, const float* __restrict__ mask,
    const float* __restrict__ gamma, const float* __restrict__ beta,
    const float* __restrict__ wa, const float* __restrict__ wb,
    __hip_bfloat16* __restrict__ A_ws, __hip_bfloat16* __restrict__ B_ws){
  __shared__ union {
    u16   X[128*64];     // 16KB bf16 LN'd [s][m], byte = s*128 + (m*2 ^ ((s&7)<<4))
    float T[64*128];     // 32KB f32 [col][s], byte = col*512 + (s*4 ^ ((col&7)<<4))
  } sh;
  __shared__ float ln_mk[128];

  const int tid = threadIdx.x, w = tid >> 6, l = tid & 63;
  const int hi = l >> 5, ln = l & 31;
  const int n = blockIdx.x;

  if (tid < 128) ln_mk[tid] = mask[tid*N_PTS + n];

  const float g  = gamma[l];
  const float be = beta[l];

  // ---- LN phase: wave w handles s = w*16 .. w*16+15, lanes = feature m ----
  #pragma unroll
  for (int t = 0; t < 16; ++t){
    int s = w*16 + t;
    float x = msa[((size_t)s*N_PTS + n)*CM + l];
    float sum = x;
    #pragma unroll
    for (int m = 1; m < 64; m <<= 1) sum += __shfl_xor(sum, m, 64);
    float mu = sum * (1.0f/64.0f);
    float dx = x - mu;
    float vs = dx*dx;
    #pragma unroll
    for (int m = 1; m < 64; m <<= 1) vs += __shfl_xor(vs, m, 64);
    float rstd = rsqrtf(vs*(1.0f/64.0f) + 1e-5f);
    float xn = dx*rstd*g + be;
    *(u16*)((char*)sh.X + s*128 + ((l*2) ^ ((s&7)<<4))) = bf16bits(xn);
  }
  __syncthreads();

  // ---- proj GEMM: [128 s][64 m] x [64 m][32 c] per matrix; wave = (mb = w>>1, mat = w&1) ----
  const int mb = w >> 1, mat = w & 1;
  const float* W = mat ? wb : wa;
  f32x16 pacc;
  #pragma unroll
  for (int r = 0; r < 16; ++r) pacc[r] = 0.f;
  #pragma unroll
  for (int ks = 0; ks < 4; ++ks){
    int srow = mb*32 + ln;
    bf16x8 aF = lds_frag(sh.X, srow*128 + (((ks*32 + hi*16)) ^ ((srow&7)<<4)));
    union { u16 s[8]; bf16x8 v; } bx;
    #pragma unroll
    for (int e = 0; e < 8; ++e){
      int m = ks*16 + hi*8 + e;
      bx.s[e] = bf16bits(W[m*C_DIM + ln]);
    }
    pacc = __builtin_amdgcn_mfma_f32_32x32x16_bf16(aF, bx.v, pacc, 0, 0, 0);
  }
  __syncthreads();   // X dead

  // ---- acc -> T (f32, masked) ----
  const int col = mat*32 + ln;
  #pragma unroll
  for (int r = 0; r < 16; ++r){
    int rr = (r & 3) + ((r >> 2) << 3) + (hi << 2);
    int s = mb*32 + rr;
    *(float*)((char*)sh.T + col*512 + ((s*4) ^ ((col&7)<<4))) = pacc[r] * ln_mk[s];
  }
  __syncthreads();

  // ---- coalesced write-out: thread -> (col2 = tid>>3, s-chunk sc = tid&7), 32B each ----
  {
    int col2 = tid >> 3, sc = tid & 7;
    __hip_bfloat16* O = (col2 < 32) ? A_ws : B_ws;
    int row = n*C_DIM + (col2 & 31);
    u16 outv[16];
    #pragma unroll
    for (int q = 0; q < 4; ++q){
      union { uint4 u4; float f[4]; } rd;
      rd.u4 = *(const uint4*)((const char*)sh.T + col2*512 + ((sc*64 + q*16) ^ ((col2&7)<<4)));
      #pragma unroll
      for (int e = 0; e < 4; ++e) outv[q*4 + e] = bf16bits(rd.f[e]);
    }
    uint4 pk0, pk1;
    u32* pw = (u32*)&pk0;
    #pragma unroll
    for (int q = 0; q < 4; ++q) pw[q] = (u32)outv[2*q] | ((u32)outv[2*q+1] << 16);
    u32* pw1 = (u32*)&pk1;
    #pragma unroll
    for (int q = 0; q < 4; ++q) pw1[q] = (u32)outv[8 + 2*q] | ((u32)outv[8 + 2*q+1] << 16);
    *(uint4*)((char*)O + (size_t)row*256 + sc*32)      = pk0;
    *(uint4*)((char*)O + (size_t)row*256 + sc*32 + 16) = pk1;
  }
}

// ---------------- kernel 2: fused ----------------
// grid (48,48), 512 threads (8 waves). Tile = 8x8 (i,j) pairs = 64 pairs.
__global__ __launch_bounds__(512, 1) void k_fused(
    const __hip_bfloat16* __restrict__ A_ws, const __hip_bfloat16* __restrict__ B_ws,
    const __hip_bfloat16* __restrict__ Wt,  const float* __restrict__ b_out,
    const float* __restrict__ mask, float* __restrict__ out){
  __shared__ union {
    struct { u16 A[256*128]; u16 B[256*128]; } s1;   // 64KB + 64KB slabs
    struct { u16 P[64*1024]; } s2;                   // 128KB P (pos-ordered, swizzled)
  } sh;
  __shared__ float nrm[64];

  const int tid = threadIdx.x;
  const int w = tid >> 6, l = tid & 63;
  const int hi = l >> 5, ln = l & 31;
  const int bi = blockIdx.x, bj = blockIdx.y;

  // ---- per-pair mask norm: 8 threads per pair ----
  {
    int p = tid >> 3, part = tid & 7;
    int i = bi*8 + (p >> 3), jj = bj*8 + (p & 7);
    float a = 0.f;
    #pragma unroll
    for (int s = part*16; s < part*16 + 16; ++s)
      a += mask[s*N_PTS + i] * mask[s*N_PTS + jj];
    a += __shfl_xor(a, 1, 64);
    a += __shfl_xor(a, 2, 64);
    a += __shfl_xor(a, 4, 64);
    if (part == 0) nrm[p] = a;
  }

  // ---- stage A/B slabs into LDS (swizzled dst, linear src) ----
  const char* Asrc = (const char*)(A_ws + (size_t)bi*256*S_DIM);   // 64KB contiguous
  const char* Bsrc = (const char*)(B_ws + (size_t)bj*256*S_DIM);
  u16* shA = sh.s1.A;
  u16* shB = sh.s1.B;
  #pragma unroll
  for (int it = 0; it < 8; ++it){
    int o = (it*512 + tid) * 16;
    int row = o >> 8, kb = o & 255;
    int dst = row*256 + (kb ^ ((row & 15) << 4));
    *(uint4*)((char*)shA + dst) = *(const uint4*)(Asrc + o);
    *(uint4*)((char*)shB + dst) = *(const uint4*)(Bsrc + o);
  }
  __syncthreads();

  // ---- stage B: 256x256 over K=128; 8 waves (2x4); wave = 128x64 = 4x2 blocks of 32 ----
  const int wr = w >> 2, wc = w & 3;
  f32x16 acc[4][2];
  #pragma unroll
  for (int mb = 0; mb < 4; ++mb)
    #pragma unroll
    for (int nb = 0; nb < 2; ++nb)
      #pragma unroll
      for (int r = 0; r < 16; ++r) acc[mb][nb][r] = 0.f;

  #pragma unroll
  for (int ks = 0; ks < 8; ++ks){
    const int k0b = ks*32 + hi*16;
    bf16x8 aF[4], bF[2];
    #pragma unroll
    for (int mb = 0; mb < 4; ++mb){
      int m = wr*128 + mb*32 + ln;
      aF[mb] = lds_frag(shA, m*256 + (k0b ^ ((m & 15) << 4)));
    }
    #pragma unroll
    for (int nb = 0; nb < 2; ++nb){
      int n = wc*64 + nb*32 + ln;
      bF[nb] = lds_frag(shB, n*256 + (k0b ^ ((n & 15) << 4)));
    }
    #pragma unroll
    for (int mb = 0; mb < 4; ++mb)
      #pragma unroll
      for (int nb = 0; nb < 2; ++nb)
        acc[mb][nb] = __builtin_amdgcn_mfma_f32_32x32x16_bf16(aF[mb], bF[nb], acc[mb][nb], 0, 0, 0);
  }
  __syncthreads();   // slab reads done before P overwrites

  // ---- write P (pos layout, b64-packed, full wave) ----
  char* shP = (char*)sh.s2.P;
  #pragma unroll
  for (int mb = 0; mb < 4; ++mb)
    #pragma unroll
    for (int nb = 0; nb < 2; ++nb){
      int p = (wr*4 + mb)*8 + (wc*2 + nb);
      int base = p*2048, sw = (p & 15) << 4;
      #pragma unroll
      for (int g = 0; g < 4; ++g){
        u32 lo   = (u32)bf16bits(acc[mb][nb][4*g + 0]) | ((u32)bf16bits(acc[mb][nb][4*g + 1]) << 16);
        u32 hi32 = (u32)bf16bits(acc[mb][nb][4*g + 2]) | ((u32)bf16bits(acc[mb][nb][4*g + 3]) << 16);
        uint2 v; v.x = lo; v.y = hi32;
        int off = ((2*g + hi)*256 + ln*8) ^ sw;
        *(uint2*)(shP + base + off) = v;
      }
    }

  // ---- stage C prologue: issue 8-deep Wt register pipeline BEFORE the barrier ----
  const int cr = w >> 2, cc = w & 3;
  const char* wbase = (const char*)Wt + (size_t)(cc*32 + ln)*2048 + hi*64;
  uint4 wreg[8];
  #pragma unroll
  for (int u = 0; u < 8; ++u)
    wreg[u] = *(const uint4*)(wbase + (u >> 2)*128 + (u & 3)*16);
  __syncthreads();

  // ---- stage C: z[p][z'] = P[p,:] . Wt_perm[z',:], K=1024, software-pipelined ----
  f32x16 zca, zcb;
  #pragma unroll
  for (int r = 0; r < 16; ++r){ zca[r] = 0.f; zcb[r] = 0.f; }

  const char* prow = shP + (cr*32 + ln)*2048;
  const int sw2 = (ln & 15) << 4;

  #pragma unroll
  for (int kb = 0; kb < 8; ++kb){
    #pragma unroll
    for (int u = 0; u < 8; ++u){
      int ks = kb*8 + u;
      bf16x8 aF = lds_frag(prow, (ks*32 + hi*16) ^ sw2);
      union { uint4 q; bf16x8 v; } bx; bx.q = wreg[u];
      if (u & 1) zcb = __builtin_amdgcn_mfma_f32_32x32x16_bf16(aF, bx.v, zcb, 0, 0, 0);
      else       zca = __builtin_amdgcn_mfma_f32_32x32x16_bf16(aF, bx.v, zca, 0, 0, 0);
      if (kb < 7){
        int kn = ks + 8;
        wreg[u] = *(const uint4*)(wbase + (kn >> 2)*128 + (kn & 3)*16);
      }
    }
  }
  #pragma unroll
  for (int r = 0; r < 16; ++r) zca[r] += zcb[r];

  // ---- epilogue ----
  const int z = cc*32 + ln;
  const float bo = b_out[z];
  #pragma unroll
  for (int r = 0; r < 16; ++r){
    int p = cr*32 + (r & 3) + ((r >> 2) << 3) + (hi << 2);
    int i = bi*8 + (p >> 3), j = bj*8 + (p & 7);
    float val = (zca[r] + bo) / (nrm[p] + 0.001f);
    out[((size_t)i*N_PTS + j)*CZ + z] = val;
  }
}

extern "C" void kernel_launch(void* const* d_in, const int* in_sizes, int n_in,
                              void* d_out, int out_size, void* d_ws, size_t ws_size,
                              hipStream_t stream) {
  (void)in_sizes; (void)n_in; (void)out_size; (void)ws_size;
  const float* msa   = (const float*)d_in[0];
  const float* mask  = (const float*)d_in[1];
  const float* gamma = (const float*)d_in[2];
  const float* beta  = (const float*)d_in[3];
  const float* wa    = (const float*)d_in[4];
  const float* wb    = (const float*)d_in[5];
  const float* wout  = (const float*)d_in[6];
  const float* bout  = (const float*)d_in[7];

  __hip_bfloat16* A_ws = (__hip_bfloat16*)d_ws;              // [12288][128] bf16
  __hip_bfloat16* B_ws = A_ws + (size_t)NC*S_DIM;            // [12288][128] bf16
  __hip_bfloat16* Wt   = B_ws + (size_t)NC*S_DIM;            // [128][1024] bf16 (pos-permuted)
  float* outp = (float*)d_out;                               // [384][384][128] f32

  k_wt<<<512, 256, 0, stream>>>(wout, Wt);
  k_lnproj<<<N_PTS, 512, 0, stream>>>(msa, mask, gamma, beta, wa, wb, A_ws, B_ws);
  dim3 g2(48, 48, 1);
  k_fused<<<g2, 512, 0, stream>>>(A_ws, B_ws, Wt, bout, mask, outp);
}